// Round 11
// baseline (83.487 us; speedup 1.0000x reference)
//
#include <hip/hip_runtime.h>

#define HD __device__ __forceinline__

namespace {

constexpr int H = 1080, W = 1920, HW = H * W;
constexpr float FXc = 1000.0f, FYc = 1000.0f;
constexpr float D_COS = 0.867f, D_DIFF = 0.35f, D_Z = 0.05f, D_FARZ = 12.3f;
constexpr int NBH = 256;    // hist blocks
constexpr int NBINS = 1024; // fp16 bits>>5; loss < 4.0 -> bin <= 543; padded to 1024

struct F3 { float x, y, z; };
HD F3 fsub(F3 a, F3 b) { return {a.x - b.x, a.y - b.y, a.z - b.z}; }
HD float fdot(F3 a, F3 b) { return a.x * b.x + a.y * b.y + a.z * b.z; }
HD F3 fcross(F3 a, F3 b) {
  return {a.y * b.z - a.z * b.y, a.z * b.x - a.x * b.z, a.x * b.y - a.y * b.x};
}

union HalfU { unsigned short u; _Float16 h; };
HD unsigned short to_h16(float f) { HalfU x; x.h = (_Float16)f; return x.u; }
HD float from_h16(unsigned short u) { HalfU x; x.u = u; return (float)x.h; }

HD F3 mkpt2(float ux, float vy, float d) {
  float ad = fabsf(d);
  F3 p;
  p.x = ux * ad / FXc;
  p.y = vy * ad / FYc;
  p.z = d;
  return p;
}

HD F3 mkpt(int j, float d) {
  int v = j / W;
  int u = j - v * W;
  return mkpt2((float)(u - W / 2), (float)(v - H / 2), d);
}

// Core per-(group,batch) computation. Returns fp16 loss bits (0xFFFF if unmasked).
HD unsigned short vnl_elem(F3 A, F3 Bp, F3 C, F3 P0, F3 P1, F3 P2) {
  F3 e12 = fsub(Bp, A), e13 = fsub(C, A), e23 = fsub(C, Bp);
  float d00 = fdot(e12, e12), d11 = fdot(e13, e13), d22 = fdot(e23, e23);
  float n0 = sqrtf(d00), n1 = sqrtf(d11), n2 = sqrtf(d22);
  int cnt = 0;
  cnt += (d00 > D_COS * (n0 * n0 + 1e-8f)) ? 1 : 0;
  cnt += (d11 > D_COS * (n1 * n1 + 1e-8f)) ? 1 : 0;
  cnt += (d22 > D_COS * (n2 * n2 + 1e-8f)) ? 1 : 0;
  cnt += (fabsf(fdot(e12, e13)) > D_COS * (n0 * n1 + 1e-8f)) ? 2 : 0;
  cnt += (fabsf(fdot(e12, e23)) > D_COS * (n0 * n2 + 1e-8f)) ? 2 : 0;
  cnt += (fabsf(fdot(e13, e23)) > D_COS * (n1 * n2 + 1e-8f)) ? 2 : 0;
  bool mask_cos = cnt > 3;
  bool mask_pad = (A.z > D_Z) && (Bp.z > D_Z) && (C.z > D_Z);
  bool mask_far = (A.z < D_FARZ) && (Bp.z < D_FARZ) && (C.z < D_FARZ);
  bool mx = fabsf(e12.x) < D_DIFF || fabsf(e13.x) < D_DIFF || fabsf(e23.x) < D_DIFF;
  bool my = fabsf(e12.y) < D_DIFF || fabsf(e13.y) < D_DIFF || fabsf(e23.y) < D_DIFF;
  bool mz = fabsf(e12.z) < D_DIFF || fabsf(e13.z) < D_DIFF || fabsf(e23.z) < D_DIFF;
  bool masked = mask_pad && mask_far && !((mx && my && mz) || mask_cos);

  // reference's z_zero broadcast semantics:
  // if point c's z == 0, coordinate c of ALL points := 1e-4
  if (P0.z == 0.f) { P0.x = 1e-4f; P1.x = 1e-4f; P2.x = 1e-4f; }
  if (P1.z == 0.f) { P0.y = 1e-4f; P1.y = 1e-4f; P2.y = 1e-4f; }
  if (P2.z == 0.f) { P0.z = 1e-4f; P1.z = 1e-4f; P2.z = 1e-4f; }

  F3 ngt = fcross(e12, e13);
  float lg = sqrtf(fdot(ngt, ngt));
  lg += (lg == 0.f) ? 0.01f : 0.f;
  F3 q12 = fsub(P1, P0), q13 = fsub(P2, P0);
  F3 npr = fcross(q12, q13);
  float lp = sqrtf(fdot(npr, npr));
  lp += (lp == 0.f) ? 0.01f : 0.f;
  float ig = 1.0f / lg, ip = 1.0f / lp;
  float l = fabsf(ngt.x * ig - npr.x * ip) + fabsf(ngt.y * ig - npr.y * ip) +
            fabsf(ngt.z * ig - npr.z * ip);
  return masked ? to_h16(l) : (unsigned short)0xFFFFu;
}

union PxU {
  uint4 u;
  _Float16 h[8];
};

// ---- packed fast path (B == 4): [HW] x {gt[0..3], pred[0..3]} fp16 = 16B/pixel ----
// Also zeroes the global histogram + ticket (folds the memset dispatch).
__global__ void vnl_pack(const float* __restrict__ pred, const float* __restrict__ gt,
                         uint4* __restrict__ pk, unsigned long long* __restrict__ gh,
                         unsigned* __restrict__ ticket) {
  int j = blockIdx.x * blockDim.x + threadIdx.x;
  if (j < NBINS) gh[j] = 0ull;
  if (j == NBINS) *ticket = 0u;
  if (j >= HW) return;
  PxU x;
  x.h[0] = (_Float16)gt[j];
  x.h[1] = (_Float16)gt[HW + j];
  x.h[2] = (_Float16)gt[2 * HW + j];
  x.h[3] = (_Float16)gt[3 * HW + j];
  x.h[4] = (_Float16)pred[j];
  x.h[5] = (_Float16)pred[HW + j];
  x.h[6] = (_Float16)pred[2 * HW + j];
  x.h[7] = (_Float16)pred[3 * HW + j];
  pk[j] = x.u;
}

// 1 group/thread, block=128; 4 batch losses stored as one ushort4 (8B).
// pk gathers via sc0 (device-coherent -> L1-bypass) inline asm: no 128B L1
// line fill per 16B random gather.
__global__ void __launch_bounds__(128) vnl_main4(
    const uint4* __restrict__ pk, const int* __restrict__ p1,
    const int* __restrict__ p2, const int* __restrict__ p3,
    ushort4* __restrict__ ub4, int G) {
  int g = blockIdx.x * blockDim.x + threadIdx.x;
  if (g >= G) return;
  int j0 = p1[g], j1 = p2[g], j2 = p3[g];
  unsigned off0 = (unsigned)j0 * 16u;
  unsigned off1 = (unsigned)j1 * 16u;
  unsigned off2 = (unsigned)j2 * 16u;
  uint4 u0, u1, u2;
  asm volatile(
      "global_load_dwordx4 %0, %3, %6 sc0\n\t"
      "global_load_dwordx4 %1, %4, %6 sc0\n\t"
      "global_load_dwordx4 %2, %5, %6 sc0\n\t"
      "s_waitcnt vmcnt(0)"
      : "=&v"(u0), "=&v"(u1), "=&v"(u2)
      : "v"(off0), "v"(off1), "v"(off2), "s"(pk));
  PxU x0, x1, x2;
  x0.u = u0;
  x1.u = u1;
  x2.u = u2;
  int vr0 = j0 / W, vr1 = j1 / W, vr2 = j2 / W;
  float ux0 = (float)(j0 - vr0 * W - W / 2), vy0 = (float)(vr0 - H / 2);
  float ux1 = (float)(j1 - vr1 * W - W / 2), vy1 = (float)(vr1 - H / 2);
  float ux2 = (float)(j2 - vr2 * W - W / 2), vy2 = (float)(vr2 - H / 2);
  unsigned short r[4];
#pragma unroll
  for (int b = 0; b < 4; ++b) {
    F3 A = mkpt2(ux0, vy0, (float)x0.h[b]);
    F3 Bp = mkpt2(ux1, vy1, (float)x1.h[b]);
    F3 C = mkpt2(ux2, vy2, (float)x2.h[b]);
    F3 P0 = mkpt2(ux0, vy0, (float)x0.h[4 + b]);
    F3 P1 = mkpt2(ux1, vy1, (float)x1.h[4 + b]);
    F3 P2 = mkpt2(ux2, vy2, (float)x2.h[4 + b]);
    r[b] = vnl_elem(A, Bp, C, P0, P1, P2);
  }
  ushort4 o;
  o.x = r[0]; o.y = r[1]; o.z = r[2]; o.w = r[3];
  ub4[g] = o;
}

// ---- fallback scalar path (any B) ----
__global__ void vnl_main(const float* __restrict__ pred, const float* __restrict__ gt,
                         const int* __restrict__ p1, const int* __restrict__ p2,
                         const int* __restrict__ p3, unsigned short* __restrict__ ub,
                         int G, int N) {
  int i = blockIdx.x * blockDim.x + threadIdx.x;
  if (i >= N) return;
  int b = i / G;
  int g = i - b * G;
  int j1 = p1[g], j2 = p2[g], j3 = p3[g];
  const float* gb = gt + (size_t)b * HW;
  const float* pb = pred + (size_t)b * HW;
  ub[i] = vnl_elem(mkpt(j1, gb[j1]), mkpt(j2, gb[j2]), mkpt(j3, gb[j3]),
                   mkpt(j1, pb[j1]), mkpt(j2, pb[j2]), mkpt(j3, pb[j3]));
}

// One packed u64 LDS atomic per element: (count<<48) | round(loss * 2^16).
// Block count <= ~6.5K < 2^16; block sum < 6.5K*227K < 2^31. Safe.
HD void hbin(unsigned hv, unsigned long long* hb) {
  if (hv != 0xFFFFu) {
    unsigned b = hv >> 5;
    b = b < (unsigned)NBINS ? b : (unsigned)(NBINS - 1);
    float lf = from_h16((unsigned short)hv);
    unsigned q = __float2uint_rn(lf * 65536.0f);
    atomicAdd(&hb[b], (1ull << 48) | (unsigned long long)q);
  }
}

// ---- fused: per-block LDS u64 hist (8KB) -> global merge (cnt<<41 | sum:
// global cnt < 2^23, sum < 1.66M*227K ~ 3.8e11 < 2^41) -> last block scans ----
__global__ void __launch_bounds__(512) vnl_histscan(
    const unsigned short* __restrict__ ub, unsigned long long* __restrict__ gh,
    unsigned* __restrict__ ticket, int N, int vec8, float* __restrict__ out) {
  __shared__ unsigned long long hb[NBINS];
  int tid = threadIdx.x;
  for (int i = tid; i < NBINS; i += 512) hb[i] = 0ull;
  __syncthreads();
  if (vec8) {
    const uint4* u4 = (const uint4*)ub;
    int M = N >> 3;
    for (int i = blockIdx.x * 512 + tid; i < M; i += NBH * 512) {
      uint4 v = u4[i];
      hbin(v.x & 0xFFFFu, hb); hbin(v.x >> 16, hb);
      hbin(v.y & 0xFFFFu, hb); hbin(v.y >> 16, hb);
      hbin(v.z & 0xFFFFu, hb); hbin(v.z >> 16, hb);
      hbin(v.w & 0xFFFFu, hb); hbin(v.w >> 16, hb);
    }
  } else {
    for (int i = blockIdx.x * 512 + tid; i < N; i += NBH * 512)
      hbin(ub[i], hb);
  }
  __syncthreads();
  for (int i = tid; i < NBINS; i += 512) {
    unsigned long long v = hb[i];
    if (v) {
      unsigned long long c = v >> 48;
      unsigned long long s = v & 0xFFFFFFFFFFFFull;
      atomicAdd(&gh[i], (c << 41) | s);
    }
  }
  __threadfence();
  __shared__ unsigned is_last;
  __syncthreads();
  if (tid == 0) is_last = (atomicAdd(ticket, 1u) == (unsigned)(NBH - 1)) ? 1u : 0u;
  __syncthreads();
  if (!is_last) return;

  // Final phase: coherent re-read of merged bins, 512-thread scan (BPT=2).
  constexpr int BPT = NBINS / 512;  // 2
  __shared__ unsigned tsum[512];
  __shared__ double dsum[512];
  unsigned cb[BPT];
  double sb[BPT];
  unsigned s = 0;
  double d = 0.0;
#pragma unroll
  for (int jj = 0; jj < BPT; ++jj) {
    unsigned long long v = atomicAdd(&gh[tid * BPT + jj], 0ull);
    cb[jj] = (unsigned)(v >> 41);
    sb[jj] = (double)(v & 0x1FFFFFFFFFFull) * (1.0 / 65536.0);
    s += cb[jj];
    d += sb[jj];
  }
  tsum[tid] = s;
  dsum[tid] = d;
  __syncthreads();
  for (int off = 1; off < 512; off <<= 1) {
    unsigned v = (tid >= off) ? tsum[tid - off] : 0u;
    double w = (tid >= off) ? dsum[tid - off] : 0.0;
    __syncthreads();
    tsum[tid] += v;
    dsum[tid] += w;
    __syncthreads();
  }
  unsigned V = tsum[511];
  double S_all = dsum[511];
  unsigned k = V >> 2;
  if (V == 0) {
    if (tid == 0) out[0] = 0.f;
    return;
  }
  if (k == 0) {
    if (tid == 0) out[0] = (float)(S_all / (double)V);
    return;
  }
  unsigned base = tsum[tid] - s;
  if (tsum[tid] >= k && base < k) {  // exactly one winner
    unsigned run = base;
    double acc = dsum[tid] - d;
#pragma unroll
    for (int jj = 0; jj < BPT; ++jj) {
      unsigned c = cb[jj];
      if (run + c >= k) {
        unsigned bin = (unsigned)(tid * BPT + jj);
        double tmid = (double)from_h16((unsigned short)((bin << 5) | 16u));
        double sum_keep = S_all - acc - (double)(k - run) * tmid;
        unsigned denom = V - k;
        if (denom < 1) denom = 1;
        out[0] = (float)(sum_keep / (double)denom);
        break;
      }
      run += c;
      acc += sb[jj];
    }
  }
}

}  // namespace

extern "C" void kernel_launch(void* const* d_in, const int* in_sizes, int n_in,
                              void* d_out, int out_size, void* d_ws, size_t ws_size,
                              hipStream_t stream) {
  const float* pred = (const float*)d_in[0];
  const float* gt = (const float*)d_in[1];
  const int* p1 = (const int*)d_in[2];
  const int* p2 = (const int*)d_in[3];
  const int* p3 = (const int*)d_in[4];
  int B = in_sizes[0] / HW;
  int G = in_sizes[2];
  int N = B * G;

  char* ws = (char*)d_ws;
  size_t pk_bytes = (size_t)HW * 16;
  size_t ub_bytes = ((size_t)N * 2 + 255) & ~(size_t)255;
  size_t gh_bytes = (size_t)NBINS * 8;
  size_t need_fast = pk_bytes + ub_bytes + gh_bytes + 512;
  bool fast = (B == 4) && (ws_size >= need_fast);

  char* p = ws;
  uint4* pk = nullptr;
  if (fast) { pk = (uint4*)p; p += pk_bytes; }
  unsigned short* ub = (unsigned short*)p; p += ub_bytes;
  unsigned long long* gh = (unsigned long long*)p; p += gh_bytes;
  unsigned* ticket = (unsigned*)p;

  if (fast) {
    vnl_pack<<<(HW + 255) / 256, 256, 0, stream>>>(pred, gt, pk, gh, ticket);
    vnl_main4<<<(G + 127) / 128, 128, 0, stream>>>(pk, p1, p2, p3, (ushort4*)ub, G);
  } else {
    hipMemsetAsync(gh, 0, gh_bytes + 256, stream);
    vnl_main<<<(N + 255) / 256, 256, 0, stream>>>(pred, gt, p1, p2, p3, ub, G, N);
  }
  int vec8 = (N % 8 == 0) ? 1 : 0;
  vnl_histscan<<<NBH, 512, 0, stream>>>(ub, gh, ticket, N, vec8, (float*)d_out);
}

// Round 12
// 57.867 us; speedup vs baseline: 1.4427x; 1.4427x over previous
//
#include <hip/hip_runtime.h>

#define HD __device__ __forceinline__

namespace {

constexpr int H = 1080, W = 1920, HW = H * W;
constexpr float FXc = 1000.0f, FYc = 1000.0f;
constexpr float D_COS = 0.867f, D_DIFF = 0.35f, D_Z = 0.05f, D_FARZ = 12.3f;
constexpr int NBH = 256;   // hist blocks
constexpr int NBINS = 768; // fp16 bits>>5; loss < 4.0 -> bin <= 543; padded to 768

struct F3 { float x, y, z; };
HD F3 fsub(F3 a, F3 b) { return {a.x - b.x, a.y - b.y, a.z - b.z}; }
HD float fdot(F3 a, F3 b) { return a.x * b.x + a.y * b.y + a.z * b.z; }
HD F3 fcross(F3 a, F3 b) {
  return {a.y * b.z - a.z * b.y, a.z * b.x - a.x * b.z, a.x * b.y - a.y * b.x};
}

union HalfU { unsigned short u; _Float16 h; };
HD unsigned short to_h16(float f) { HalfU x; x.h = (_Float16)f; return x.u; }
HD float from_h16(unsigned short u) { HalfU x; x.u = u; return (float)x.h; }

HD F3 mkpt2(float ux, float vy, float d) {
  float ad = fabsf(d);
  F3 p;
  p.x = ux * ad / FXc;
  p.y = vy * ad / FYc;
  p.z = d;
  return p;
}

HD F3 mkpt(int j, float d) {
  int v = j / W;
  int u = j - v * W;
  return mkpt2((float)(u - W / 2), (float)(v - H / 2), d);
}

// Core per-(group,batch) computation. Returns fp16 loss bits (0xFFFF if unmasked).
// cosine test via |dot| > D_COS*(na*nb+eps) (denominator > 0); energy matrix is
// symmetric bitwise, so 3 off-diagonal tests count double. Normals via 2 rcp.
HD unsigned short vnl_elem(F3 A, F3 Bp, F3 C, F3 P0, F3 P1, F3 P2) {
  F3 e12 = fsub(Bp, A), e13 = fsub(C, A), e23 = fsub(C, Bp);
  float d00 = fdot(e12, e12), d11 = fdot(e13, e13), d22 = fdot(e23, e23);
  float n0 = sqrtf(d00), n1 = sqrtf(d11), n2 = sqrtf(d22);
  int cnt = 0;
  cnt += (d00 > D_COS * (n0 * n0 + 1e-8f)) ? 1 : 0;
  cnt += (d11 > D_COS * (n1 * n1 + 1e-8f)) ? 1 : 0;
  cnt += (d22 > D_COS * (n2 * n2 + 1e-8f)) ? 1 : 0;
  cnt += (fabsf(fdot(e12, e13)) > D_COS * (n0 * n1 + 1e-8f)) ? 2 : 0;
  cnt += (fabsf(fdot(e12, e23)) > D_COS * (n0 * n2 + 1e-8f)) ? 2 : 0;
  cnt += (fabsf(fdot(e13, e23)) > D_COS * (n1 * n2 + 1e-8f)) ? 2 : 0;
  bool mask_cos = cnt > 3;
  bool mask_pad = (A.z > D_Z) && (Bp.z > D_Z) && (C.z > D_Z);
  bool mask_far = (A.z < D_FARZ) && (Bp.z < D_FARZ) && (C.z < D_FARZ);
  bool mx = fabsf(e12.x) < D_DIFF || fabsf(e13.x) < D_DIFF || fabsf(e23.x) < D_DIFF;
  bool my = fabsf(e12.y) < D_DIFF || fabsf(e13.y) < D_DIFF || fabsf(e23.y) < D_DIFF;
  bool mz = fabsf(e12.z) < D_DIFF || fabsf(e13.z) < D_DIFF || fabsf(e23.z) < D_DIFF;
  bool masked = mask_pad && mask_far && !((mx && my && mz) || mask_cos);

  // reference's z_zero broadcast semantics:
  // if point c's z == 0, coordinate c of ALL points := 1e-4
  if (P0.z == 0.f) { P0.x = 1e-4f; P1.x = 1e-4f; P2.x = 1e-4f; }
  if (P1.z == 0.f) { P0.y = 1e-4f; P1.y = 1e-4f; P2.y = 1e-4f; }
  if (P2.z == 0.f) { P0.z = 1e-4f; P1.z = 1e-4f; P2.z = 1e-4f; }

  F3 ngt = fcross(e12, e13);
  float lg = sqrtf(fdot(ngt, ngt));
  lg += (lg == 0.f) ? 0.01f : 0.f;
  F3 q12 = fsub(P1, P0), q13 = fsub(P2, P0);
  F3 npr = fcross(q12, q13);
  float lp = sqrtf(fdot(npr, npr));
  lp += (lp == 0.f) ? 0.01f : 0.f;
  float ig = 1.0f / lg, ip = 1.0f / lp;
  float l = fabsf(ngt.x * ig - npr.x * ip) + fabsf(ngt.y * ig - npr.y * ip) +
            fabsf(ngt.z * ig - npr.z * ip);
  return masked ? to_h16(l) : (unsigned short)0xFFFFu;
}

union PxU {
  uint4 u;
  _Float16 h[8];
};

// ---- packed fast path (B == 4): [HW] x {gt[0..3], pred[0..3]} fp16 = 16B/pixel ----
// Also zeroes the global histogram (folds the memset dispatch).
__global__ void vnl_pack(const float* __restrict__ pred, const float* __restrict__ gt,
                         uint4* __restrict__ pk, unsigned long long* __restrict__ gh) {
  int j = blockIdx.x * blockDim.x + threadIdx.x;
  if (j < NBINS) gh[j] = 0ull;
  if (j >= HW) return;
  PxU x;
  x.h[0] = (_Float16)gt[j];
  x.h[1] = (_Float16)gt[HW + j];
  x.h[2] = (_Float16)gt[2 * HW + j];
  x.h[3] = (_Float16)gt[3 * HW + j];
  x.h[4] = (_Float16)pred[j];
  x.h[5] = (_Float16)pred[HW + j];
  x.h[6] = (_Float16)pred[2 * HW + j];
  x.h[7] = (_Float16)pred[3 * HW + j];
  pk[j] = x.u;
}

// 1 group/thread, block=128; 4 batch losses stored as one ushort4 (8B).
__global__ void __launch_bounds__(128) vnl_main4(
    const uint4* __restrict__ pk, const int* __restrict__ p1,
    const int* __restrict__ p2, const int* __restrict__ p3,
    ushort4* __restrict__ ub4, int G) {
  int g = blockIdx.x * blockDim.x + threadIdx.x;
  if (g >= G) return;
  int j0 = p1[g], j1 = p2[g], j2 = p3[g];
  PxU x0, x1, x2;
  x0.u = pk[j0];
  x1.u = pk[j1];
  x2.u = pk[j2];
  int vr0 = j0 / W, vr1 = j1 / W, vr2 = j2 / W;
  float ux0 = (float)(j0 - vr0 * W - W / 2), vy0 = (float)(vr0 - H / 2);
  float ux1 = (float)(j1 - vr1 * W - W / 2), vy1 = (float)(vr1 - H / 2);
  float ux2 = (float)(j2 - vr2 * W - W / 2), vy2 = (float)(vr2 - H / 2);
  unsigned short r[4];
#pragma unroll
  for (int b = 0; b < 4; ++b) {
    F3 A = mkpt2(ux0, vy0, (float)x0.h[b]);
    F3 Bp = mkpt2(ux1, vy1, (float)x1.h[b]);
    F3 C = mkpt2(ux2, vy2, (float)x2.h[b]);
    F3 P0 = mkpt2(ux0, vy0, (float)x0.h[4 + b]);
    F3 P1 = mkpt2(ux1, vy1, (float)x1.h[4 + b]);
    F3 P2 = mkpt2(ux2, vy2, (float)x2.h[4 + b]);
    r[b] = vnl_elem(A, Bp, C, P0, P1, P2);
  }
  ushort4 o;
  o.x = r[0]; o.y = r[1]; o.z = r[2]; o.w = r[3];
  ub4[g] = o;
}

// ---- fallback scalar path (any B) ----
__global__ void vnl_main(const float* __restrict__ pred, const float* __restrict__ gt,
                         const int* __restrict__ p1, const int* __restrict__ p2,
                         const int* __restrict__ p3, unsigned short* __restrict__ ub,
                         int G, int N) {
  int i = blockIdx.x * blockDim.x + threadIdx.x;
  if (i >= N) return;
  int b = i / G;
  int g = i - b * G;
  int j1 = p1[g], j2 = p2[g], j3 = p3[g];
  const float* gb = gt + (size_t)b * HW;
  const float* pb = pred + (size_t)b * HW;
  ub[i] = vnl_elem(mkpt(j1, gb[j1]), mkpt(j2, gb[j2]), mkpt(j3, gb[j3]),
                   mkpt(j1, pb[j1]), mkpt(j2, pb[j2]), mkpt(j3, pb[j3]));
}

// One packed u64 LDS atomic per element: (count<<48) | round(loss * 2^16).
// Block count <= ~26K < 2^16; block sum < 26K*4*2^16 < 2^34. Safe.
HD void hbin(unsigned hv, unsigned long long* hb) {
  if (hv != 0xFFFFu) {
    unsigned b = hv >> 5;
    b = b < (unsigned)NBINS ? b : (unsigned)(NBINS - 1);
    float lf = from_h16((unsigned short)hv);
    unsigned q = __float2uint_rn(lf * 65536.0f);
    atomicAdd(&hb[b], (1ull << 48) | (unsigned long long)q);
  }
}

// ---- per-block LDS u64 hist (6KB) -> global merge (cnt<<41 | sum packing:
// global cnt < 2^23, global sum < 6.6M*4*2^16 = 1.7e12 < 2^41) ----
__global__ void __launch_bounds__(512) vnl_hist(
    const unsigned short* __restrict__ ub, unsigned long long* __restrict__ gh,
    int N, int vec8) {
  __shared__ unsigned long long hb[NBINS];
  int tid = threadIdx.x;
  for (int i = tid; i < NBINS; i += 512) hb[i] = 0ull;
  __syncthreads();
  if (vec8) {
    const uint4* u4 = (const uint4*)ub;
    int M = N >> 3;
    for (int i = blockIdx.x * 512 + tid; i < M; i += NBH * 512) {
      uint4 v = u4[i];
      hbin(v.x & 0xFFFFu, hb); hbin(v.x >> 16, hb);
      hbin(v.y & 0xFFFFu, hb); hbin(v.y >> 16, hb);
      hbin(v.z & 0xFFFFu, hb); hbin(v.z >> 16, hb);
      hbin(v.w & 0xFFFFu, hb); hbin(v.w >> 16, hb);
    }
  } else {
    for (int i = blockIdx.x * 512 + tid; i < N; i += NBH * 512)
      hbin(ub[i], hb);
  }
  __syncthreads();
  for (int i = tid; i < NBINS; i += 512) {
    unsigned long long v = hb[i];
    if (v) {
      unsigned long long c = v >> 48;
      unsigned long long s = v & 0xFFFFFFFFFFFFull;
      atomicAdd(&gh[i], (c << 41) | s);
    }
  }
}

// ---- single block, 256 threads: scan 768 bins, trimmed mean, write out ----
__global__ void vnl_scanfinal(const unsigned long long* __restrict__ gh,
                              float* __restrict__ out) {
  constexpr int BPT = NBINS / 256;  // 3
  __shared__ unsigned tsum[256];
  __shared__ double dsum[256];
  int tid = threadIdx.x;
  unsigned cb[BPT];
  double sb[BPT];
  unsigned s = 0;
  double d = 0.0;
#pragma unroll
  for (int jj = 0; jj < BPT; ++jj) {
    unsigned long long v = gh[tid * BPT + jj];
    cb[jj] = (unsigned)(v >> 41);
    sb[jj] = (double)(v & 0x1FFFFFFFFFFull) * (1.0 / 65536.0);
    s += cb[jj];
    d += sb[jj];
  }
  tsum[tid] = s;
  dsum[tid] = d;
  __syncthreads();
  for (int off = 1; off < 256; off <<= 1) {
    unsigned v = (tid >= off) ? tsum[tid - off] : 0u;
    double w = (tid >= off) ? dsum[tid - off] : 0.0;
    __syncthreads();
    tsum[tid] += v;
    dsum[tid] += w;
    __syncthreads();
  }
  unsigned V = tsum[255];
  double S_all = dsum[255];
  unsigned k = V >> 2;
  if (V == 0) {
    if (tid == 0) out[0] = 0.f;
    return;
  }
  if (k == 0) {
    if (tid == 0) out[0] = (float)(S_all / (double)V);
    return;
  }
  unsigned base = tsum[tid] - s;
  if (tsum[tid] >= k && base < k) {  // exactly one winner
    unsigned run = base;
    double acc = dsum[tid] - d;
#pragma unroll
    for (int jj = 0; jj < BPT; ++jj) {
      unsigned c = cb[jj];
      if (run + c >= k) {
        unsigned bin = (unsigned)(tid * BPT + jj);
        double tmid = (double)from_h16((unsigned short)((bin << 5) | 16u));
        double sum_keep = S_all - acc - (double)(k - run) * tmid;
        unsigned denom = V - k;
        if (denom < 1) denom = 1;
        out[0] = (float)(sum_keep / (double)denom);
        break;
      }
      run += c;
      acc += sb[jj];
    }
  }
}

}  // namespace

extern "C" void kernel_launch(void* const* d_in, const int* in_sizes, int n_in,
                              void* d_out, int out_size, void* d_ws, size_t ws_size,
                              hipStream_t stream) {
  const float* pred = (const float*)d_in[0];
  const float* gt = (const float*)d_in[1];
  const int* p1 = (const int*)d_in[2];
  const int* p2 = (const int*)d_in[3];
  const int* p3 = (const int*)d_in[4];
  int B = in_sizes[0] / HW;
  int G = in_sizes[2];
  int N = B * G;

  char* ws = (char*)d_ws;
  size_t pk_bytes = (size_t)HW * 16;
  size_t ub_bytes = ((size_t)N * 2 + 255) & ~(size_t)255;
  size_t gh_bytes = (size_t)NBINS * 8;
  size_t need_fast = pk_bytes + ub_bytes + gh_bytes + 512;
  bool fast = (B == 4) && (ws_size >= need_fast);

  char* p = ws;
  uint4* pk = nullptr;
  if (fast) { pk = (uint4*)p; p += pk_bytes; }
  unsigned short* ub = (unsigned short*)p; p += ub_bytes;
  unsigned long long* gh = (unsigned long long*)p;

  if (fast) {
    vnl_pack<<<(HW + 255) / 256, 256, 0, stream>>>(pred, gt, pk, gh);
    vnl_main4<<<(G + 127) / 128, 128, 0, stream>>>(pk, p1, p2, p3, (ushort4*)ub, G);
  } else {
    hipMemsetAsync(gh, 0, gh_bytes, stream);
    vnl_main<<<(N + 255) / 256, 256, 0, stream>>>(pred, gt, p1, p2, p3, ub, G, N);
  }
  int vec8 = (N % 8 == 0) ? 1 : 0;
  vnl_hist<<<NBH, 512, 0, stream>>>(ub, gh, N, vec8);
  vnl_scanfinal<<<1, 256, 0, stream>>>(gh, (float*)d_out);
}